// Round 7
// baseline (311.014 us; speedup 1.0000x reference)
//
#include <hip/hip_runtime.h>
#include <math.h>

#define BB 256
#define DD 128
#define CC 8000
#define EPSF 1e-12f
#define SCALEF 64.0f
#define MARGINF 0.5f

// ---------------------------------------------------------------------------
// Single-dispatch version of the proven R0 kernel. Phases 1-2 and the
// epilogue math are byte-for-byte R0 (93.6 us measured; fused ~38 us).
// The separate scale_kernel (~7 us + launch gap) is replaced by a
// WAITER-FREE per-row ticket: after wave ty stores psums[row][cblk], its
// lane 0 does fetch_add(ACQ_REL, agent) on g_tick[row] (module-load zeroed,
// monotonic across launches: exactly 32 increments/row/launch, R2-proven
// pattern). The 32nd arriver alone normalizes that row (256-thread
// cooperative, 64 KB), overlapped with other blocks' GEMMs. No block ever
// waits (R2's mistake). Release on the add publishes the wave's e-stores
// (wave-level vmcnt drain + L2 writeback); acquire invalidates before the
// winner re-reads other XCDs' stores.
// ---------------------------------------------------------------------------

__device__ int g_tick[BB];  // static storage: zeroed at module load

__global__ __launch_bounds__(256, 2) void fused_kernel(
    const float* __restrict__ embds, const float* __restrict__ w,
    const int* __restrict__ labels, float* __restrict__ out,
    float* __restrict__ psums) {
  __shared__ float neS[DD * 16];
  __shared__ float gS[DD * 16];
  __shared__ float s1S[16];
  __shared__ int labS[16];
  __shared__ int wonS[16];
  __shared__ float invS;

  int tid = threadIdx.x;
  int c0 = blockIdx.x * 256;
  int r0 = blockIdx.y * 16;

  if (tid < 16) wonS[tid] = 0;

  // ---- phase 1: local prep (16 rows x 16 threads each) ----
  {
    int r = tid >> 4;           // 0..15 local row
    int k = tid & 15;           // 0..15, each handles 8 d's
    int row = r0 + r;
    int lab = labels[row];
    const float4* e4 = (const float4*)(embds + row * DD + k * 8);
    float4 ea = e4[0], eb = e4[1];
    float ev[8] = {ea.x, ea.y, ea.z, ea.w, eb.x, eb.y, eb.z, eb.w};
    float wl[8];
    float se = 0.f, sw = 0.f, sx = 0.f;
    #pragma unroll
    for (int i = 0; i < 8; ++i) {
      wl[i] = w[(k * 8 + i) * CC + lab];
      se = fmaf(ev[i], ev[i], se);
      sw = fmaf(wl[i], wl[i], sw);
      sx = fmaf(ev[i], wl[i], sx);
    }
    // reduce within the 16-lane k-group (xor masks 1,2,4,8 stay in-group)
    #pragma unroll
    for (int off = 1; off < 16; off <<= 1) {
      se += __shfl_xor(se, off, 64);
      sw += __shfl_xor(sw, off, 64);
      sx += __shfl_xor(sx, off, 64);
    }
    float rn = rsqrtf(fmaxf(se, EPSF));
    float rl = rsqrtf(fmaxf(sw, EPSF));
    #pragma unroll
    for (int i = 0; i < 8; ++i) {
      neS[(k * 8 + i) * 16 + r] = ev[i] * rn;
      gS[(k * 8 + i) * 16 + r] = wl[i] * rl;
    }
    if (k == 0) { s1S[r] = sx * rn * rl; labS[r] = lab; }
  }
  __syncthreads();

  // ---- phase 2: dual GEMM, w streamed once per block (EXACT R0) ----
  int tx = tid & 63;
  int ty = tid >> 6;            // wave id = row group (wave-uniform)
  int c = c0 + tx * 4;
  bool cok = c < CC;
  const float4* w4 = (const float4*)w;
  int wbase = (c0 >> 2) + tx;

  float accC[4][4], accG[4][4], colsum[4];
  #pragma unroll
  for (int rr = 0; rr < 4; ++rr)
    #pragma unroll
    for (int j = 0; j < 4; ++j) { accC[rr][j] = 0.f; accG[rr][j] = 0.f; }
  #pragma unroll
  for (int j = 0; j < 4; ++j) colsum[j] = 0.f;

  #pragma unroll 8
  for (int d = 0; d < DD; ++d) {
    float4 wv = cok ? w4[d * (CC / 4) + wbase] : make_float4(0.f, 0.f, 0.f, 0.f);
    float4 a = *(const float4*)&neS[d * 16 + ty * 4];  // wave-uniform: broadcast
    float4 g = *(const float4*)&gS[d * 16 + ty * 4];
    float av[4] = {a.x, a.y, a.z, a.w};
    float gv[4] = {g.x, g.y, g.z, g.w};
    float wj[4] = {wv.x, wv.y, wv.z, wv.w};
    #pragma unroll
    for (int j = 0; j < 4; ++j) colsum[j] = fmaf(wj[j], wj[j], colsum[j]);
    #pragma unroll
    for (int rr = 0; rr < 4; ++rr) {
      #pragma unroll
      for (int j = 0; j < 4; ++j) {
        accC[rr][j] = fmaf(av[rr], wj[j], accC[rr][j]);
        accG[rr][j] = fmaf(gv[rr], wj[j], accG[rr][j]);
      }
    }
  }

  // ---- phase 3: epilogue + per-row ticket ----
  float rcj[4];
  #pragma unroll
  for (int j = 0; j < 4; ++j) rcj[j] = rsqrtf(fmaxf(colsum[j], EPSF));

  float* pen_base = out + (size_t)BB * CC;
  #pragma unroll
  for (int rr = 0; rr < 4; ++rr) {
    int lr = ty * 4 + rr;
    int row = r0 + lr;
    float s1v = s1S[lr];
    int lab = labS[lr];
    float penv[4], eo[4];
    float psum = 0.f;
    #pragma unroll
    for (int j = 0; j < 4; ++j) {
      float cs = accC[rr][j] * rcj[j];
      float gw = accG[rr][j] * rcj[j];
      float win = (s1v - cs) * rsqrtf(fmaxf(2.f - 2.f * gw, EPSF));
      if (c + j == lab) win = 0.f;
      penv[j] = MARGINF - fminf(MARGINF, win);
      float e = cok ? __expf(SCALEF * cs) : 0.f;
      eo[j] = e;
      psum += e;
    }
    if (cok) {
      size_t o4 = (size_t)row * (CC / 4) + wbase;
      ((float4*)pen_base)[o4] = make_float4(penv[0], penv[1], penv[2], penv[3]);
      ((float4*)out)[o4] = make_float4(eo[0], eo[1], eo[2], eo[3]);
    }
    // wave reduction of psum (all 64 lanes, this row)
    #pragma unroll
    for (int off = 1; off < 64; off <<= 1) psum += __shfl_xor(psum, off, 64);
    if (tx == 0) {
      __hip_atomic_store(&psums[row * 32 + blockIdx.x], psum,
                         __ATOMIC_RELAXED, __HIP_MEMORY_SCOPE_AGENT);
      // ACQ_REL: release publishes this wave's e/pen/psum stores (wave-level
      // vmcnt drain + L2 writeback); acquire makes peers' stores visible if
      // we turn out to be the 32nd (last) arriver for this row.
      int old = __hip_atomic_fetch_add(&g_tick[row], 1, __ATOMIC_ACQ_REL,
                                       __HIP_MEMORY_SCOPE_AGENT);
      if ((old & 31) == 31) wonS[lr] = 1;   // monotonic: 32 adds/row/launch
    }
  }
  __syncthreads();

  // ---- rare path: normalize rows this block won (no one waits on us) ----
  for (int lr = 0; lr < 16; ++lr) {
    if (!wonS[lr]) continue;
    int row = r0 + lr;
    // sum the 32 partials (wave 0 pattern identical to old scale_kernel)
    if (tid < 64) {
      float p = (tid < 32)
                    ? __hip_atomic_load(&psums[row * 32 + tid], __ATOMIC_RELAXED,
                                        __HIP_MEMORY_SCOPE_AGENT)
                    : 0.f;
      #pragma unroll
      for (int off = 1; off < 32; off <<= 1) p += __shfl_xor(p, off, 64);
      if (tid == 0) invS = 1.f / p;
    }
    __syncthreads();
    float inv = invS;
    float4* rowp = (float4*)out + (size_t)row * (CC / 4);
    for (int i = tid; i < CC / 4; i += 256) {
      float4 v = rowp[i];
      rowp[i] = make_float4(v.x * inv, v.y * inv, v.z * inv, v.w * inv);
    }
    __syncthreads();
  }
}

extern "C" void kernel_launch(void* const* d_in, const int* in_sizes, int n_in,
                              void* d_out, int out_size, void* d_ws, size_t ws_size,
                              hipStream_t stream) {
  const float* embds = (const float*)d_in[0];
  const float* w = (const float*)d_in[1];
  const int* labels = (const int*)d_in[2];
  float* out = (float*)d_out;
  float* psums = (float*)d_ws;    // [256][32]

  dim3 gA(32, 16);
  fused_kernel<<<gA, 256, 0, stream>>>(embds, w, labels, out, psums);
}

// Round 8
// 94.035 us; speedup vs baseline: 3.3074x; 3.3074x over previous
//
#include <hip/hip_runtime.h>
#include <math.h>

#define BB 256
#define DD 128
#define CC 8000
#define EPSF 1e-12f
#define SCALEF 64.0f
#define MARGINF 0.5f

// ---------------------------------------------------------------------------
// FINAL: byte-for-byte restore of the measured-best kernel (R0, 93.58 us).
// Session record (R1-R7): every structural change regressed —
//   R2  per-row-group device barrier:        +20 us (cross-XCD coherence)
//   R3  4 blk/CU + prefetch:                 neutral (occupancy-invariant)
//   R4  global_load_lds staging:             x6 (VALUBusy 0.07%)
//   R6  reg-staged LDS double-buffer:        x3.5 (barrier-exposed cold misses)
//   R7  per-row ticket (ACQ_REL atomics):    x6.8 (coherence round-trips)
// Composition of the 93.6 us window: ~41 us harness poison-fill dispatch +
// ~38 us fused (cold-cache latency-bound; L3 dirtied by the 256 MiB fill
// every iteration) + ~7 us scale + launch gaps.
//
// Kernel A: fused prep + dual GEMM + epilogue. Grid 32(c) x 16(r) = 512
// blocks x 256 thr (2 blocks/CU, 8 waves/CU). Per block:
//   phase 1: local prep into LDS — normalize 16 embds rows (neS), gather+
//            normalize 16 label columns of w (gS), s1 per row.
//   phase 2: dual GEMM over d streaming w (float4, L2-resident). Column
//            norms accumulated FOR FREE from the same streamed w values.
//   phase 3: epilogue — penalties written final; e = exp(64*cos) written
//            UNNORMALIZED to the logits region (arg<=64 -> fits fp32, no
//            max-subtraction needed); per-(row,cblock) partial sums stored
//            to psums (no atomics).
// ---------------------------------------------------------------------------
__global__ __launch_bounds__(256, 2) void fused_kernel(
    const float* __restrict__ embds, const float* __restrict__ w,
    const int* __restrict__ labels, float* __restrict__ out,
    float* __restrict__ psums) {
  __shared__ float neS[DD * 16];
  __shared__ float gS[DD * 16];
  __shared__ float s1S[16];
  __shared__ int labS[16];

  int tid = threadIdx.x;
  int c0 = blockIdx.x * 256;
  int r0 = blockIdx.y * 16;

  // ---- phase 1: local prep (16 rows x 16 threads each) ----
  {
    int r = tid >> 4;           // 0..15 local row
    int k = tid & 15;           // 0..15, each handles 8 d's
    int row = r0 + r;
    int lab = labels[row];
    const float4* e4 = (const float4*)(embds + row * DD + k * 8);
    float4 ea = e4[0], eb = e4[1];
    float ev[8] = {ea.x, ea.y, ea.z, ea.w, eb.x, eb.y, eb.z, eb.w};
    float wl[8];
    float se = 0.f, sw = 0.f, sx = 0.f;
    #pragma unroll
    for (int i = 0; i < 8; ++i) {
      wl[i] = w[(k * 8 + i) * CC + lab];
      se = fmaf(ev[i], ev[i], se);
      sw = fmaf(wl[i], wl[i], sw);
      sx = fmaf(ev[i], wl[i], sx);
    }
    // reduce within the 16-lane k-group (xor masks 1,2,4,8 stay in-group)
    #pragma unroll
    for (int off = 1; off < 16; off <<= 1) {
      se += __shfl_xor(se, off, 64);
      sw += __shfl_xor(sw, off, 64);
      sx += __shfl_xor(sx, off, 64);
    }
    float rn = rsqrtf(fmaxf(se, EPSF));
    float rl = rsqrtf(fmaxf(sw, EPSF));
    #pragma unroll
    for (int i = 0; i < 8; ++i) {
      neS[(k * 8 + i) * 16 + r] = ev[i] * rn;
      gS[(k * 8 + i) * 16 + r] = wl[i] * rl;
    }
    if (k == 0) { s1S[r] = sx * rn * rl; labS[r] = lab; }
  }
  __syncthreads();

  // ---- phase 2: dual GEMM, w streamed once per block ----
  int tx = tid & 63;
  int ty = tid >> 6;            // wave id = row group (wave-uniform)
  int c = c0 + tx * 4;
  bool cok = c < CC;
  const float4* w4 = (const float4*)w;
  int wbase = (c0 >> 2) + tx;

  float accC[4][4], accG[4][4], colsum[4];
  #pragma unroll
  for (int rr = 0; rr < 4; ++rr)
    #pragma unroll
    for (int j = 0; j < 4; ++j) { accC[rr][j] = 0.f; accG[rr][j] = 0.f; }
  #pragma unroll
  for (int j = 0; j < 4; ++j) colsum[j] = 0.f;

  #pragma unroll 8
  for (int d = 0; d < DD; ++d) {
    float4 wv = cok ? w4[d * (CC / 4) + wbase] : make_float4(0.f, 0.f, 0.f, 0.f);
    float4 a = *(const float4*)&neS[d * 16 + ty * 4];  // wave-uniform: broadcast
    float4 g = *(const float4*)&gS[d * 16 + ty * 4];
    float av[4] = {a.x, a.y, a.z, a.w};
    float gv[4] = {g.x, g.y, g.z, g.w};
    float wj[4] = {wv.x, wv.y, wv.z, wv.w};
    #pragma unroll
    for (int j = 0; j < 4; ++j) colsum[j] = fmaf(wj[j], wj[j], colsum[j]);
    #pragma unroll
    for (int rr = 0; rr < 4; ++rr) {
      #pragma unroll
      for (int j = 0; j < 4; ++j) {
        accC[rr][j] = fmaf(av[rr], wj[j], accC[rr][j]);
        accG[rr][j] = fmaf(gv[rr], wj[j], accG[rr][j]);
      }
    }
  }

  // ---- phase 3: epilogue ----
  float rcj[4];
  #pragma unroll
  for (int j = 0; j < 4; ++j) rcj[j] = rsqrtf(fmaxf(colsum[j], EPSF));

  float* pen_base = out + (size_t)BB * CC;
  #pragma unroll
  for (int rr = 0; rr < 4; ++rr) {
    int lr = ty * 4 + rr;
    int row = r0 + lr;
    float s1v = s1S[lr];
    int lab = labS[lr];
    float penv[4], eo[4];
    float psum = 0.f;
    #pragma unroll
    for (int j = 0; j < 4; ++j) {
      float cs = accC[rr][j] * rcj[j];
      float gw = accG[rr][j] * rcj[j];
      float win = (s1v - cs) * rsqrtf(fmaxf(2.f - 2.f * gw, EPSF));
      if (c + j == lab) win = 0.f;
      penv[j] = MARGINF - fminf(MARGINF, win);
      float e = cok ? __expf(SCALEF * cs) : 0.f;
      eo[j] = e;
      psum += e;
    }
    if (cok) {
      size_t o4 = (size_t)row * (CC / 4) + wbase;
      ((float4*)pen_base)[o4] = make_float4(penv[0], penv[1], penv[2], penv[3]);
      ((float4*)out)[o4] = make_float4(eo[0], eo[1], eo[2], eo[3]);
    }
    // wave reduction of psum (all 64 lanes, this row)
    #pragma unroll
    for (int off = 1; off < 64; off <<= 1) psum += __shfl_xor(psum, off, 64);
    if (tx == 0) psums[row * 32 + blockIdx.x] = psum;
  }
}

// ---------------------------------------------------------------------------
// Kernel B: per-row normalize. 256 blocks x 512 thr. Sum the 32 partials,
// scale the row's 8000 unnormalized e-values in place.
// ---------------------------------------------------------------------------
__global__ __launch_bounds__(512) void scale_kernel(
    float* __restrict__ out, const float* __restrict__ psums) {
  __shared__ float invS;
  int r = blockIdx.x;
  int tid = threadIdx.x;
  if (tid < 64) {
    float p = (tid < 32) ? psums[r * 32 + tid] : 0.f;
    #pragma unroll
    for (int off = 1; off < 32; off <<= 1) p += __shfl_xor(p, off, 64);
    if (tid == 0) invS = 1.f / p;
  }
  __syncthreads();
  float inv = invS;
  float4* row = (float4*)out + (size_t)r * (CC / 4);
  #pragma unroll
  for (int k = 0; k < 4; ++k) {
    int i = tid + k * 512;
    if (i < CC / 4) {
      float4 v = row[i];
      row[i] = make_float4(v.x * inv, v.y * inv, v.z * inv, v.w * inv);
    }
  }
}

extern "C" void kernel_launch(void* const* d_in, const int* in_sizes, int n_in,
                              void* d_out, int out_size, void* d_ws, size_t ws_size,
                              hipStream_t stream) {
  const float* embds = (const float*)d_in[0];
  const float* w = (const float*)d_in[1];
  const int* labels = (const int*)d_in[2];
  float* out = (float*)d_out;
  float* psums = (float*)d_ws;    // [256][32]

  dim3 gA(32, 16);
  fused_kernel<<<gA, 256, 0, stream>>>(embds, w, labels, out, psums);
  scale_kernel<<<256, 512, 0, stream>>>(out, psums);
}